// Round 1
// baseline (63502.643 us; speedup 1.0000x reference)
//
#include <hip/hip_runtime.h>

typedef _Float16 f16;
typedef _Float16 f16x2 __attribute__((ext_vector_type(2)));
typedef _Float16 f16x8 __attribute__((ext_vector_type(8)));
typedef float f32x4 __attribute__((ext_vector_type(4)));

#define B_ 64
#define S_ 1024
#define E_ 256
#define H_ 512
#define NG 1536         // 3*H packed gate rows (r | z | n)
#define TCH 128         // timesteps per chunk
#define NCHUNK (S_/TCH)
#define ROWS_CH (TCH*B_)   // 8192
#define CL_WG 32        // workgroups per cluster
#define NCL 8           // clusters (8 batches each)

__device__ __forceinline__ float sigm(float x) { return 1.f / (1.f + __expf(-x)); }

__device__ __forceinline__ float dot2(unsigned u, f16x2 h, float acc) {
#if __has_builtin(__builtin_amdgcn_fdot2)
    return __builtin_amdgcn_fdot2(__builtin_bit_cast(f16x2, u), h, acc, false);
#else
    f16x2 w = __builtin_bit_cast(f16x2, u);
    return acc + (float)w[0] * (float)h[0] + (float)w[1] * (float)h[1];
#endif
}

// ---------------- embedding gather -> fp16, rows ordered (t, b) ----------------
__global__ __launch_bounds__(256) void k_embed(const int* __restrict__ tok,
        const float* __restrict__ emb, f16* __restrict__ X, int t0) {
    int idx = blockIdx.x * 256 + threadIdx.x;     // ROWS_CH * (E_/4) units
    int r = idx >> 6;                             // chunk-local row
    int c4 = (idx & 63) << 2;
    int t = t0 + (r >> 6), b = r & 63;
    int tk = tok[b * S_ + t];
    float4 v = *reinterpret_cast<const float4*>(emb + (size_t)tk * E_ + c4);
    union { f16 h[4]; unsigned long long u; } w;
    w.h[0] = (f16)v.x; w.h[1] = (f16)v.y; w.h[2] = (f16)v.z; w.h[3] = (f16)v.w;
    *reinterpret_cast<unsigned long long*>(X + (size_t)r * E_ + c4) = w.u;
}

// ------------- pack [gate_w slice ; gi_or_gh_w] into fp16 [1536][KK] -------------
__global__ __launch_bounds__(256) void k_packW(const float* __restrict__ gw, int ld, int off,
        const float* __restrict__ g2, f16* __restrict__ W, int KK) {
    int idx = blockIdx.x * 256 + threadIdx.x;
    int per = KK >> 2;
    if (idx >= NG * per) return;
    int row = idx / per;
    int c4 = (idx % per) << 2;
    const float* src = (row < 1024) ? gw + (size_t)row * ld + off + c4
                                    : g2 + (size_t)(row - 1024) * KK + c4;
    float4 v = *reinterpret_cast<const float4*>(src);
    union { f16 h[4]; unsigned long long u; } w;
    w.h[0] = (f16)v.x; w.h[1] = (f16)v.y; w.h[2] = (f16)v.z; w.h[3] = (f16)v.w;
    *reinterpret_cast<unsigned long long*>(W + (size_t)row * KK + c4) = w.u;
}

__global__ __launch_bounds__(256) void k_packBias(const float* __restrict__ gb,
        const float* __restrict__ gib, float* __restrict__ bias) {
    int i = blockIdx.x * 256 + threadIdx.x;
    if (i < 1024) bias[i] = gb[i];
    else if (i < NG) bias[i] = gib[i - 1024];
}

// --------- GEMM: C[M,1536] = A[M,K] * Bm[1536,K]^T + bias ; fp16 in/out, fp32 acc ---------
__global__ __launch_bounds__(256) void k_gemm(const f16* __restrict__ A,
        const f16* __restrict__ Bm, const float* __restrict__ bias,
        f16* __restrict__ C, int K) {
    __shared__ f16 As[64][40];
    __shared__ f16 Bs[64][40];
    const int tid = threadIdx.x;
    const int m0 = blockIdx.y << 6, n0 = blockIdx.x << 6;
    const int w = tid >> 6, l = tid & 63;
    const int wr = (w >> 1) << 5, wc = (w & 1) << 5;
    const int srow = tid >> 2, sc8 = (tid & 3) << 3;
    const int fr = l & 15, kl = (l >> 4) << 3;
    f32x4 acc[2][2] = {};
    for (int k0 = 0; k0 < K; k0 += 32) {
        *reinterpret_cast<f16x8*>(&As[srow][sc8]) =
            *reinterpret_cast<const f16x8*>(A + (size_t)(m0 + srow) * K + k0 + sc8);
        *reinterpret_cast<f16x8*>(&Bs[srow][sc8]) =
            *reinterpret_cast<const f16x8*>(Bm + (size_t)(n0 + srow) * K + k0 + sc8);
        __syncthreads();
        f16x8 a0 = *reinterpret_cast<const f16x8*>(&As[wr + fr][kl]);
        f16x8 a1 = *reinterpret_cast<const f16x8*>(&As[wr + 16 + fr][kl]);
        f16x8 b0 = *reinterpret_cast<const f16x8*>(&Bs[wc + fr][kl]);
        f16x8 b1 = *reinterpret_cast<const f16x8*>(&Bs[wc + 16 + fr][kl]);
        acc[0][0] = __builtin_amdgcn_mfma_f32_16x16x32_f16(a0, b0, acc[0][0], 0, 0, 0);
        acc[0][1] = __builtin_amdgcn_mfma_f32_16x16x32_f16(a0, b1, acc[0][1], 0, 0, 0);
        acc[1][0] = __builtin_amdgcn_mfma_f32_16x16x32_f16(a1, b0, acc[1][0], 0, 0, 0);
        acc[1][1] = __builtin_amdgcn_mfma_f32_16x16x32_f16(a1, b1, acc[1][1], 0, 0, 0);
        __syncthreads();
    }
    for (int fm = 0; fm < 2; ++fm)
        for (int fn = 0; fn < 2; ++fn) {
            int col = n0 + wc + (fn << 4) + fr;
            float bv = bias[col];
            for (int j = 0; j < 4; ++j) {
                int rowg = m0 + wr + (fm << 4) + ((l >> 4) << 2) + j;
                C[(size_t)rowg * NG + col] = (f16)(acc[fm][fn][j] + bv);
            }
        }
}

// --------------------------- persistent GRU recurrence ---------------------------
// 256 WGs = 8 clusters x 32 WGs. Cluster c owns batches [8c, 8c+8); WG g owns
// 16 contiguous i-indices. W rows (r_i, z_i, n_i) live in LDS for the whole kernel.
// Per step: 3 dots over h (fp16 dot2, K split across lane pairs), gate math,
// double-buffered h exchange with release/acquire + per-cluster atomic counter.
__global__ __launch_bounds__(256) void k_recur(const f16* __restrict__ Wh,
        const f16* __restrict__ Z, const float* __restrict__ ghb,
        f16* h_buf, f16* H0out, int* cnt, int t0, int nsteps) {
    __shared__ f16 Wl[3][16][516];
    const int wg = blockIdx.x;
    const int c = wg >> 5, g = wg & 31;
    const int i0 = g << 4;
    const int tid = threadIdx.x;
    const int q = tid & 1, il = (tid >> 1) & 15, bl = tid >> 5;
    const int b = (c << 3) + bl;
    const int i = i0 + il;
    // stage this WG's 48 weight rows into LDS (once)
    for (int idx = tid; idx < 48 * 128; idx += 256) {
        int r = idx >> 7, c4 = (idx & 127) << 2;
        int gate = r >> 4, rl = r & 15;
        *reinterpret_cast<uint2*>(&Wl[gate][rl][c4]) =
            *reinterpret_cast<const uint2*>(Wh + (size_t)(gate * H_ + i0 + rl) * H_ + c4);
    }
    __syncthreads();
    int* mycnt = cnt + (c << 6);
    for (int sl = 0; sl < nsteps; ++sl) {
        const int s = t0 + sl;
        const int p = s & 1;
        if (tid == 0) {
            const int target = CL_WG * s;
            while (__hip_atomic_load(mycnt, __ATOMIC_ACQUIRE, __HIP_MEMORY_SCOPE_AGENT) < target)
                __builtin_amdgcn_s_sleep(1);
        }
        __syncthreads();
        const f16* hb = h_buf + ((size_t)p * B_ + b) * H_ + (q << 8);
        const int kbase = q << 8;
        float a0 = 0.f, a1 = 0.f, a2 = 0.f;
        #pragma unroll 4
        for (int k = 0; k < 256; k += 4) {
            uint2 hv = *reinterpret_cast<const uint2*>(hb + k);
            uint2 w0 = *reinterpret_cast<const uint2*>(&Wl[0][il][kbase + k]);
            uint2 w1 = *reinterpret_cast<const uint2*>(&Wl[1][il][kbase + k]);
            uint2 w2 = *reinterpret_cast<const uint2*>(&Wl[2][il][kbase + k]);
            f16x2 h01 = __builtin_bit_cast(f16x2, hv.x);
            f16x2 h23 = __builtin_bit_cast(f16x2, hv.y);
            a0 = dot2(w0.x, h01, a0); a0 = dot2(w0.y, h23, a0);
            a1 = dot2(w1.x, h01, a1); a1 = dot2(w1.y, h23, a1);
            a2 = dot2(w2.x, h01, a2); a2 = dot2(w2.y, h23, a2);
        }
        float dr = a0 + __shfl_xor(a0, 1);
        float dz = a1 + __shfl_xor(a1, 1);
        float dn = a2 + __shfl_xor(a2, 1);
        if (q == 0) {
            size_t zrow = ((size_t)sl * B_ + b) * NG;
            float zr = (float)Z[zrow + i];
            float zz = (float)Z[zrow + H_ + i];
            float zn = (float)Z[zrow + 2 * H_ + i];
            float hol = (float)h_buf[((size_t)p * B_ + b) * H_ + i];
            float r = sigm(zr + dr);
            float z = sigm(zz + dz);
            float n = tanhf(zn + r * (dn + ghb[i]));
            float hn = (1.f - z) * n + z * hol;
            f16 hh = (f16)hn;
            h_buf[((size_t)(p ^ 1) * B_ + b) * H_ + i] = hh;
            if (H0out) H0out[((size_t)sl * B_ + b) * H_ + i] = hh;
        }
        __threadfence();   // agent release: drain stores + L2 writeback
        __syncthreads();
        if (tid == 0)
            __hip_atomic_fetch_add(mycnt, 1, __ATOMIC_RELEASE, __HIP_MEMORY_SCOPE_AGENT);
    }
}

// ------------------------------- final head -------------------------------
__global__ __launch_bounds__(64) void k_final(const f16* __restrict__ h,
        const float* __restrict__ fcw, const float* __restrict__ fcb,
        float* __restrict__ out) {
    int b = threadIdx.x;
    float acc = fcb[0];
    for (int k = 0; k < H_; ++k) acc += (float)h[(size_t)b * H_ + k] * fcw[k];
    out[b] = sigm(acc);
}

extern "C" void kernel_launch(void* const* d_in, const int* in_sizes, int n_in,
                              void* d_out, int out_size, void* d_ws, size_t ws_size,
                              hipStream_t stream) {
    (void)in_sizes; (void)n_in; (void)out_size; (void)ws_size;
    const int*   tokens = (const int*)d_in[0];
    const float* emb  = (const float*)d_in[1];
    const float* fc_w = (const float*)d_in[2];
    const float* fc_b = (const float*)d_in[3];
    const float* gw0  = (const float*)d_in[4];
    const float* gb0  = (const float*)d_in[5];
    const float* giw0 = (const float*)d_in[6];
    const float* gib0 = (const float*)d_in[7];
    const float* ghw0 = (const float*)d_in[8];
    const float* ghb0 = (const float*)d_in[9];
    const float* gw1  = (const float*)d_in[10];
    const float* gb1  = (const float*)d_in[11];
    const float* giw1 = (const float*)d_in[12];
    const float* gib1 = (const float*)d_in[13];
    const float* ghw1 = (const float*)d_in[14];
    const float* ghb1 = (const float*)d_in[15];

    char* base = (char*)d_ws;
    size_t off = 0;
    auto carve = [&](size_t bytes) {
        char* p = base + off;
        off = (off + bytes + 255) & ~(size_t)255;
        return p;
    };
    f16*   Wx0   = (f16*)carve((size_t)NG * 256 * 2);
    f16*   Wh0   = (f16*)carve((size_t)NG * 512 * 2);
    f16*   Wx1   = (f16*)carve((size_t)NG * 512 * 2);
    f16*   Wh1   = (f16*)carve((size_t)NG * 512 * 2);
    float* bias0 = (float*)carve(NG * 4);
    float* bias1 = (float*)carve(NG * 4);
    f16*   hbuf0 = (f16*)carve((size_t)2 * B_ * H_ * 2);
    f16*   hbuf1 = (f16*)carve((size_t)2 * B_ * H_ * 2);
    int*   cnt   = (int*)carve((size_t)2 * NCL * 64 * 4);
    f16*   Xc    = (f16*)carve((size_t)ROWS_CH * 256 * 2);
    f16*   Zc0   = (f16*)carve((size_t)ROWS_CH * NG * 2);
    f16*   H0c   = (f16*)carve((size_t)ROWS_CH * 512 * 2);
    f16*   Zc1   = (f16*)carve((size_t)ROWS_CH * NG * 2);

    hipMemsetAsync(hbuf0, 0, (size_t)2 * B_ * H_ * 2, stream);
    hipMemsetAsync(hbuf1, 0, (size_t)2 * B_ * H_ * 2, stream);
    hipMemsetAsync(cnt, 0, (size_t)2 * NCL * 64 * 4, stream);

    k_packW<<<384, 256, 0, stream>>>(gw0, 768, 0,    giw0, Wx0, 256);
    k_packW<<<768, 256, 0, stream>>>(gw0, 768, 256,  ghw0, Wh0, 512);
    k_packW<<<768, 256, 0, stream>>>(gw1, 1024, 0,   giw1, Wx1, 512);
    k_packW<<<768, 256, 0, stream>>>(gw1, 1024, 512, ghw1, Wh1, 512);
    k_packBias<<<6, 256, 0, stream>>>(gb0, gib0, bias0);
    k_packBias<<<6, 256, 0, stream>>>(gb1, gib1, bias1);

    dim3 gemmGrid(NG / 64, ROWS_CH / 64);   // (24, 128)
    for (int ch = 0; ch < NCHUNK; ++ch) {
        int t0 = ch * TCH;
        k_embed<<<ROWS_CH * 64 / 256, 256, 0, stream>>>(tokens, emb, Xc, t0);
        k_gemm<<<gemmGrid, 256, 0, stream>>>(Xc, Wx0, bias0, Zc0, 256);
        k_recur<<<256, 256, 0, stream>>>(Wh0, Zc0, ghb0, hbuf0, H0c, cnt, t0, TCH);
        k_gemm<<<gemmGrid, 256, 0, stream>>>(H0c, Wx1, bias1, Zc1, 512);
        k_recur<<<256, 256, 0, stream>>>(Wh1, Zc1, ghb1, hbuf1, nullptr, cnt + NCL * 64, t0, TCH);
    }
    k_final<<<1, 64, 0, stream>>>(hbuf1, fc_w, fc_b, (float*)d_out);
}

// Round 2
// 7347.089 us; speedup vs baseline: 8.6432x; 8.6432x over previous
//
#include <hip/hip_runtime.h>

typedef _Float16 f16;
typedef _Float16 f16x2 __attribute__((ext_vector_type(2)));
typedef _Float16 f16x8 __attribute__((ext_vector_type(8)));
typedef float f32x4 __attribute__((ext_vector_type(4)));

#define B_ 64
#define S_ 1024
#define E_ 256
#define H_ 512
#define NG 1536         // 3*H packed gate rows (r | z | n)
#define TCH 128         // timesteps per chunk
#define NCHUNK (S_/TCH)
#define ROWS_CH (TCH*B_)   // 8192

__device__ __forceinline__ float sigm(float x) { return 1.f / (1.f + __expf(-x)); }

__device__ __forceinline__ float dot2(unsigned u, unsigned hv, float acc) {
#if __has_builtin(__builtin_amdgcn_fdot2)
    return __builtin_amdgcn_fdot2(__builtin_bit_cast(f16x2, u),
                                  __builtin_bit_cast(f16x2, hv), acc, false);
#else
    f16x2 w = __builtin_bit_cast(f16x2, u);
    f16x2 h = __builtin_bit_cast(f16x2, hv);
    return acc + (float)w[0] * (float)h[0] + (float)w[1] * (float)h[1];
#endif
}

// ---------------- embedding gather -> fp16, rows ordered (t, b) ----------------
__global__ __launch_bounds__(256) void k_embed(const int* __restrict__ tok,
        const float* __restrict__ emb, f16* __restrict__ X, int t0) {
    int idx = blockIdx.x * 256 + threadIdx.x;     // ROWS_CH * (E_/4) units
    int r = idx >> 6;                             // chunk-local row
    int c4 = (idx & 63) << 2;
    int t = t0 + (r >> 6), b = r & 63;
    int tk = tok[b * S_ + t];
    float4 v = *reinterpret_cast<const float4*>(emb + (size_t)tk * E_ + c4);
    union { f16 h[4]; unsigned long long u; } w;
    w.h[0] = (f16)v.x; w.h[1] = (f16)v.y; w.h[2] = (f16)v.z; w.h[3] = (f16)v.w;
    *reinterpret_cast<unsigned long long*>(X + (size_t)r * E_ + c4) = w.u;
}

// ------------- pack [gate_w slice ; gi_or_gh_w] into fp16 [1536][KK] -------------
__global__ __launch_bounds__(256) void k_packW(const float* __restrict__ gw, int ld, int off,
        const float* __restrict__ g2, f16* __restrict__ W, int KK) {
    int idx = blockIdx.x * 256 + threadIdx.x;
    int per = KK >> 2;
    if (idx >= NG * per) return;
    int row = idx / per;
    int c4 = (idx % per) << 2;
    const float* src = (row < 1024) ? gw + (size_t)row * ld + off + c4
                                    : g2 + (size_t)(row - 1024) * KK + c4;
    float4 v = *reinterpret_cast<const float4*>(src);
    union { f16 h[4]; unsigned long long u; } w;
    w.h[0] = (f16)v.x; w.h[1] = (f16)v.y; w.h[2] = (f16)v.z; w.h[3] = (f16)v.w;
    *reinterpret_cast<unsigned long long*>(W + (size_t)row * KK + c4) = w.u;
}

__global__ __launch_bounds__(256) void k_packBias(const float* __restrict__ gb,
        const float* __restrict__ gib, float* __restrict__ bias) {
    int i = blockIdx.x * 256 + threadIdx.x;
    if (i < 1024) bias[i] = gb[i];
    else if (i < NG) bias[i] = gib[i - 1024];
}

// --------- GEMM: C[M,1536] = A[M,K] * Bm[1536,K]^T + bias ; fp16 in/out, fp32 acc ---------
__global__ __launch_bounds__(256) void k_gemm(const f16* __restrict__ A,
        const f16* __restrict__ Bm, const float* __restrict__ bias,
        f16* __restrict__ C, int K) {
    __shared__ f16 As[64][40];
    __shared__ f16 Bs[64][40];
    const int tid = threadIdx.x;
    const int m0 = blockIdx.y << 6, n0 = blockIdx.x << 6;
    const int w = tid >> 6, l = tid & 63;
    const int wr = (w >> 1) << 5, wc = (w & 1) << 5;
    const int srow = tid >> 2, sc8 = (tid & 3) << 3;
    const int fr = l & 15, kl = (l >> 4) << 3;
    f32x4 acc[2][2] = {};
    for (int k0 = 0; k0 < K; k0 += 32) {
        *reinterpret_cast<f16x8*>(&As[srow][sc8]) =
            *reinterpret_cast<const f16x8*>(A + (size_t)(m0 + srow) * K + k0 + sc8);
        *reinterpret_cast<f16x8*>(&Bs[srow][sc8]) =
            *reinterpret_cast<const f16x8*>(Bm + (size_t)(n0 + srow) * K + k0 + sc8);
        __syncthreads();
        f16x8 a0 = *reinterpret_cast<const f16x8*>(&As[wr + fr][kl]);
        f16x8 a1 = *reinterpret_cast<const f16x8*>(&As[wr + 16 + fr][kl]);
        f16x8 b0 = *reinterpret_cast<const f16x8*>(&Bs[wc + fr][kl]);
        f16x8 b1 = *reinterpret_cast<const f16x8*>(&Bs[wc + 16 + fr][kl]);
        acc[0][0] = __builtin_amdgcn_mfma_f32_16x16x32_f16(a0, b0, acc[0][0], 0, 0, 0);
        acc[0][1] = __builtin_amdgcn_mfma_f32_16x16x32_f16(a0, b1, acc[0][1], 0, 0, 0);
        acc[1][0] = __builtin_amdgcn_mfma_f32_16x16x32_f16(a1, b0, acc[1][0], 0, 0, 0);
        acc[1][1] = __builtin_amdgcn_mfma_f32_16x16x32_f16(a1, b1, acc[1][1], 0, 0, 0);
        __syncthreads();
    }
    for (int fm = 0; fm < 2; ++fm)
        for (int fn = 0; fn < 2; ++fn) {
            int col = n0 + wc + (fn << 4) + fr;
            float bv = bias[col];
            for (int j = 0; j < 4; ++j) {
                int rowg = m0 + wr + (fm << 4) + ((l >> 4) << 2) + j;
                C[(size_t)rowg * NG + col] = (f16)(acc[fm][fn][j] + bv);
            }
        }
}

// --------------------------- persistent GRU recurrence, both layers ---------------------------
// 512 WGs x 128 thr. Decode: c=blk&7 (cluster->XCD), l=(blk>>3)&1 (layer), gg=blk>>4 (0..31).
// WG owns 16 outputs [gg*16, gg*16+16). Weights LDS-resident in bank-friendly padded layout.
// Cross-WG h exchange + counters use RELAXED agent-scope atomics only (cache-bypassing);
// ordering comes from __syncthreads' implicit vmcnt-drain. No agent fences in the hot loop.
__global__ __launch_bounds__(128) void k_recur2(
        const f16* __restrict__ Wh0p, const f16* __restrict__ Wh1p,
        const f16* __restrict__ Z0, const f16* __restrict__ Z1,
        const float* __restrict__ ghb0, const float* __restrict__ ghb1,
        f16* hb0, f16* hb1, f16* __restrict__ H0out, int* cnt,
        int t00, int n0, int t01, int n1) {
    __shared__ __align__(16) f16 WS[4 * 6368];   // [q][ (gate*16+row)*132 ] : bank = 4*row+q (2-way, free)
    __shared__ __align__(16) f16 HS[4 * 1120];   // [q][ b*136 ] staged h
    __shared__ __align__(16) f16 hx[8][16];      // gathered h_next slice
    const int blk = blockIdx.x;
    const int c = blk & 7;
    const int rr_ = blk >> 3;
    const int l = rr_ & 1;
    const int gg = rr_ >> 1;                     // 0..31
    const int nsteps = l ? n1 : n0;
    if (nsteps <= 0) return;
    const int t0 = l ? t01 : t00;
    const f16* __restrict__ Wh = l ? Wh1p : Wh0p;
    const f16* __restrict__ Z  = l ? Z1 : Z0;
    const float* __restrict__ ghb = l ? ghb1 : ghb0;
    f16* hbuf = l ? hb1 : hb0;
    int* mycnt = cnt + ((l * 8 + c) << 5);       // 128B apart
    const int i0 = gg << 4;
    const int tid = threadIdx.x;
    const int q = tid & 3, il = (tid >> 2) & 15, bl = tid >> 6;  // 4 x 16 x 2

    // ---- stage this WG's 48 weight rows (3 gates x 16) into padded LDS, once ----
    for (int idx = tid; idx < 6144; idx += 128) {
        int e = idx << 2;                        // f16 linear in [3][16][512]
        int g = e >> 13;
        int rem = e & 8191;
        int wrow = rem >> 9;
        int kk = rem & 511;
        uint2 v = *reinterpret_cast<const uint2*>(
            Wh + ((size_t)(g * H_ + i0 + wrow)) * H_ + kk);
        *reinterpret_cast<uint2*>(
            &WS[(kk >> 7) * 6368 + (g * 16 + wrow) * 132 + (kk & 127)]) = v;
    }
    const float gbias = ghb[i0 + il];
    const int wb = q * 6368 + il * 132;
    unsigned long long* hb64 = reinterpret_cast<unsigned long long*>(hbuf);

    for (int sl = 0; sl < nsteps; ++sl) {
        const int s = t0 + sl;
        const int p = s & 1;
        // ---- Z prefetch (independent of h; hides under spin+stage) ----
        float zr[4], zz[4], zn[4];
        if (q == 0) {
            #pragma unroll
            for (int j = 0; j < 4; ++j) {
                int b = bl + 2 * j;
                size_t zrow = ((size_t)sl * 64 + c * 8 + b) * NG;
                zr[j] = (float)Z[zrow + i0 + il];
                zz[j] = (float)Z[zrow + H_ + i0 + il];
                zn[j] = (float)Z[zrow + 2 * H_ + i0 + il];
            }
        }
        // ---- wait for all cluster WGs to finish step s-1 (relaxed polls only) ----
        if (tid == 0) {
            const int target = s << 5;           // 32 WGs per cluster
            while (__hip_atomic_load(mycnt, __ATOMIC_RELAXED, __HIP_MEMORY_SCOPE_AGENT) < target) {}
        }
        __syncthreads();
        // ---- stage h[p] (8 batches x 512) into LDS via bypassing atomic loads ----
        {
            const size_t srcbase = ((size_t)p * 64 + c * 8) * 128;   // ull units
            #pragma unroll
            for (int rr = 0; rr < 8; ++rr) {
                int j = tid + (rr << 7);
                int b = j >> 7, cc = j & 127;
                unsigned long long v = __hip_atomic_load(hb64 + srcbase + (size_t)b * 128 + cc,
                        __ATOMIC_RELAXED, __HIP_MEMORY_SCOPE_AGENT);
                int kf = cc << 2;
                *reinterpret_cast<uint2*>(&HS[(kf >> 7) * 1120 + b * 136 + (kf & 127)]) =
                    __builtin_bit_cast(uint2, v);
            }
        }
        __syncthreads();
        // ---- dot: 3 gates x 4 batches, K-quarter per thread ----
        float acc[3][4];
        #pragma unroll
        for (int g = 0; g < 3; ++g)
            #pragma unroll
            for (int j = 0; j < 4; ++j) acc[g][j] = 0.f;
        const int hq = q * 1120;
        #pragma unroll 8
        for (int k = 0; k < 128; k += 4) {
            uint2 w0 = *reinterpret_cast<const uint2*>(&WS[wb + k]);
            uint2 w1 = *reinterpret_cast<const uint2*>(&WS[wb + 2112 + k]);
            uint2 w2 = *reinterpret_cast<const uint2*>(&WS[wb + 4224 + k]);
            #pragma unroll
            for (int j = 0; j < 4; ++j) {
                uint2 hv = *reinterpret_cast<const uint2*>(&HS[hq + (bl + 2 * j) * 136 + k]);
                acc[0][j] = dot2(w0.x, hv.x, acc[0][j]);
                acc[0][j] = dot2(w0.y, hv.y, acc[0][j]);
                acc[1][j] = dot2(w1.x, hv.x, acc[1][j]);
                acc[1][j] = dot2(w1.y, hv.y, acc[1][j]);
                acc[2][j] = dot2(w2.x, hv.x, acc[2][j]);
                acc[2][j] = dot2(w2.y, hv.y, acc[2][j]);
            }
        }
        // ---- reduce across the 4 q-lanes ----
        #pragma unroll
        for (int g = 0; g < 3; ++g)
            #pragma unroll
            for (int j = 0; j < 4; ++j) {
                float v = acc[g][j];
                v += __shfl_xor(v, 1);
                v += __shfl_xor(v, 2);
                acc[g][j] = v;
            }
        // ---- gate math on q==0 lanes ----
        if (q == 0) {
            const int i = i0 + il;
            #pragma unroll
            for (int j = 0; j < 4; ++j) {
                int b = bl + 2 * j;
                float r = sigm(zr[j] + acc[0][j]);
                float z = sigm(zz[j] + acc[1][j]);
                float hold = (float)HS[(i >> 7) * 1120 + b * 136 + (i & 127)];
                float n = tanhf(zn[j] + r * (acc[2][j] + gbias));
                float hn = (1.f - z) * n + z * hold;
                hx[b][il] = (f16)hn;
            }
        }
        __syncthreads();
        // ---- gather + publish h_next (bypassing atomic stores) + H0 trajectory ----
        if (tid < 32) {
            int b = tid >> 2, m = tid & 3;
            uint2 v = *reinterpret_cast<const uint2*>(&hx[b][m << 2]);
            size_t dst = ((size_t)(p ^ 1) * 64 + c * 8 + b) * 128 + (i0 >> 2) + m;
            __hip_atomic_store(hb64 + dst, __builtin_bit_cast(unsigned long long, v),
                               __ATOMIC_RELAXED, __HIP_MEMORY_SCOPE_AGENT);
            if (l == 0)
                *reinterpret_cast<uint2*>(
                    H0out + ((size_t)sl * 64 + c * 8 + b) * H_ + i0 + (m << 2)) = v;
        }
        __syncthreads();   // compiler drains vmcnt(0) before s_barrier -> stores complete
        if (tid == 0)
            __hip_atomic_fetch_add(mycnt, 1, __ATOMIC_RELAXED, __HIP_MEMORY_SCOPE_AGENT);
    }
}

// ------------------------------- final head -------------------------------
__global__ __launch_bounds__(64) void k_final(const f16* __restrict__ h,
        const float* __restrict__ fcw, const float* __restrict__ fcb,
        float* __restrict__ out) {
    int b = threadIdx.x;
    float acc = fcb[0];
    for (int k = 0; k < H_; ++k) acc += (float)h[(size_t)b * H_ + k] * fcw[k];
    out[b] = sigm(acc);
}

extern "C" void kernel_launch(void* const* d_in, const int* in_sizes, int n_in,
                              void* d_out, int out_size, void* d_ws, size_t ws_size,
                              hipStream_t stream) {
    (void)in_sizes; (void)n_in; (void)out_size; (void)ws_size;
    const int*   tokens = (const int*)d_in[0];
    const float* emb  = (const float*)d_in[1];
    const float* fc_w = (const float*)d_in[2];
    const float* fc_b = (const float*)d_in[3];
    const float* gw0  = (const float*)d_in[4];
    const float* gb0  = (const float*)d_in[5];
    const float* giw0 = (const float*)d_in[6];
    const float* gib0 = (const float*)d_in[7];
    const float* ghw0 = (const float*)d_in[8];
    const float* ghb0 = (const float*)d_in[9];
    const float* gw1  = (const float*)d_in[10];
    const float* gb1  = (const float*)d_in[11];
    const float* giw1 = (const float*)d_in[12];
    const float* gib1 = (const float*)d_in[13];
    const float* ghw1 = (const float*)d_in[14];
    const float* ghb1 = (const float*)d_in[15];

    char* base = (char*)d_ws;
    size_t off = 0;
    auto carve = [&](size_t bytes) {
        char* p = base + off;
        off = (off + bytes + 255) & ~(size_t)255;
        return p;
    };
    f16*   Wx0   = (f16*)carve((size_t)NG * 256 * 2);
    f16*   Wh0   = (f16*)carve((size_t)NG * 512 * 2);
    f16*   Wx1   = (f16*)carve((size_t)NG * 512 * 2);
    f16*   Wh1   = (f16*)carve((size_t)NG * 512 * 2);
    float* bias0 = (float*)carve(NG * 4);
    float* bias1 = (float*)carve(NG * 4);
    f16*   hbuf0 = (f16*)carve((size_t)2 * B_ * H_ * 2);
    f16*   hbuf1 = (f16*)carve((size_t)2 * B_ * H_ * 2);
    int*   cnt   = (int*)carve((size_t)16 * 32 * 4);
    f16*   Xc    = (f16*)carve((size_t)ROWS_CH * 256 * 2);
    f16*   Zc0   = (f16*)carve((size_t)ROWS_CH * NG * 2);
    f16*   H0c   = (f16*)carve((size_t)ROWS_CH * 512 * 2);
    f16*   Zc1   = (f16*)carve((size_t)ROWS_CH * NG * 2);

    hipMemsetAsync(hbuf0, 0, (size_t)2 * B_ * H_ * 2, stream);
    hipMemsetAsync(hbuf1, 0, (size_t)2 * B_ * H_ * 2, stream);
    hipMemsetAsync(cnt, 0, (size_t)16 * 32 * 4, stream);

    k_packW<<<384, 256, 0, stream>>>(gw0, 768, 0,    giw0, Wx0, 256);
    k_packW<<<768, 256, 0, stream>>>(gw0, 768, 256,  ghw0, Wh0, 512);
    k_packW<<<768, 256, 0, stream>>>(gw1, 1024, 0,   giw1, Wx1, 512);
    k_packW<<<768, 256, 0, stream>>>(gw1, 1024, 512, ghw1, Wh1, 512);
    k_packBias<<<6, 256, 0, stream>>>(gb0, gib0, bias0);
    k_packBias<<<6, 256, 0, stream>>>(gb1, gib1, bias1);

    dim3 gemmGrid(NG / 64, ROWS_CH / 64);   // (24, 128)
    for (int ch = 0; ch < NCHUNK; ++ch) {
        int t0 = ch * TCH;
        k_embed<<<ROWS_CH * 64 / 256, 256, 0, stream>>>(tokens, emb, Xc, t0);
        k_gemm<<<gemmGrid, 256, 0, stream>>>(Xc, Wx0, bias0, Zc0, 256);
        // L0 of chunk ch runs concurrently with L1 of chunk ch-1
        k_recur2<<<512, 128, 0, stream>>>(Wh0, Wh1, Zc0, Zc1, ghb0, ghb1,
                                          hbuf0, hbuf1, H0c, cnt,
                                          t0, TCH, t0 - TCH, ch ? TCH : 0);
        k_gemm<<<gemmGrid, 256, 0, stream>>>(H0c, Wx1, bias1, Zc1, 512);
    }
    // drain: last chunk of layer 1
    k_recur2<<<512, 128, 0, stream>>>(Wh0, Wh1, Zc0, Zc1, ghb0, ghb1,
                                      hbuf0, hbuf1, H0c, cnt,
                                      0, 0, (NCHUNK - 1) * TCH, TCH);
    k_final<<<1, 64, 0, stream>>>(hbuf1, fc_w, fc_b, (float*)d_out);
}

// Round 3
// 3343.948 us; speedup vs baseline: 18.9903x; 2.1971x over previous
//
#include <hip/hip_runtime.h>

typedef _Float16 f16;
typedef _Float16 f16x8 __attribute__((ext_vector_type(8)));
typedef float f32x4 __attribute__((ext_vector_type(4)));

#define B_ 64
#define S_ 1024
#define E_ 256
#define H_ 512
#define NG 1536         // 3*H packed gate rows (r | z | n)
#define TCH 128         // timesteps per chunk
#define NCHUNK (S_/TCH)
#define ROWS_CH (TCH*B_)   // 8192
#define HS_LD 536       // LDS stride for h rows: 536*2B -> bank step 12 (<=2-way)

__device__ __forceinline__ float sigm(float x) { return 1.f / (1.f + __expf(-x)); }

// ---------------- embedding gather -> fp16, rows ordered (t, b) ----------------
__global__ __launch_bounds__(256) void k_embed(const int* __restrict__ tok,
        const float* __restrict__ emb, f16* __restrict__ X, int t0) {
    int idx = blockIdx.x * 256 + threadIdx.x;     // ROWS_CH * (E_/4) units
    int r = idx >> 6;                             // chunk-local row
    int c4 = (idx & 63) << 2;
    int t = t0 + (r >> 6), b = r & 63;
    int tk = tok[b * S_ + t];
    float4 v = *reinterpret_cast<const float4*>(emb + (size_t)tk * E_ + c4);
    union { f16 h[4]; unsigned long long u; } w;
    w.h[0] = (f16)v.x; w.h[1] = (f16)v.y; w.h[2] = (f16)v.z; w.h[3] = (f16)v.w;
    *reinterpret_cast<unsigned long long*>(X + (size_t)r * E_ + c4) = w.u;
}

// ------------- pack [gate_w slice ; gi_or_gh_w] into fp16 [1536][KK] -------------
__global__ __launch_bounds__(256) void k_packW(const float* __restrict__ gw, int ld, int off,
        const float* __restrict__ g2, f16* __restrict__ W, int KK) {
    int idx = blockIdx.x * 256 + threadIdx.x;
    int per = KK >> 2;
    if (idx >= NG * per) return;
    int row = idx / per;
    int c4 = (idx % per) << 2;
    const float* src = (row < 1024) ? gw + (size_t)row * ld + off + c4
                                    : g2 + (size_t)(row - 1024) * KK + c4;
    float4 v = *reinterpret_cast<const float4*>(src);
    union { f16 h[4]; unsigned long long u; } w;
    w.h[0] = (f16)v.x; w.h[1] = (f16)v.y; w.h[2] = (f16)v.z; w.h[3] = (f16)v.w;
    *reinterpret_cast<unsigned long long*>(W + (size_t)row * KK + c4) = w.u;
}

__global__ __launch_bounds__(256) void k_packBias(const float* __restrict__ gb,
        const float* __restrict__ gib, float* __restrict__ bias) {
    int i = blockIdx.x * 256 + threadIdx.x;
    if (i < 1024) bias[i] = gb[i];
    else if (i < NG) bias[i] = gib[i - 1024];
}

// --------- GEMM: C[M,1536] = A[M,K] * Bm[1536,K]^T + bias ; fp16 in/out, fp32 acc ---------
__global__ __launch_bounds__(256) void k_gemm(const f16* __restrict__ A,
        const f16* __restrict__ Bm, const float* __restrict__ bias,
        f16* __restrict__ C, int K) {
    __shared__ f16 As[64][40];
    __shared__ f16 Bs[64][40];
    const int tid = threadIdx.x;
    const int m0 = blockIdx.y << 6, n0 = blockIdx.x << 6;
    const int w = tid >> 6, l = tid & 63;
    const int wr = (w >> 1) << 5, wc = (w & 1) << 5;
    const int srow = tid >> 2, sc8 = (tid & 3) << 3;
    const int fr = l & 15, kl = (l >> 4) << 3;
    f32x4 acc[2][2] = {};
    for (int k0 = 0; k0 < K; k0 += 32) {
        *reinterpret_cast<f16x8*>(&As[srow][sc8]) =
            *reinterpret_cast<const f16x8*>(A + (size_t)(m0 + srow) * K + k0 + sc8);
        *reinterpret_cast<f16x8*>(&Bs[srow][sc8]) =
            *reinterpret_cast<const f16x8*>(Bm + (size_t)(n0 + srow) * K + k0 + sc8);
        __syncthreads();
        f16x8 a0 = *reinterpret_cast<const f16x8*>(&As[wr + fr][kl]);
        f16x8 a1 = *reinterpret_cast<const f16x8*>(&As[wr + 16 + fr][kl]);
        f16x8 b0 = *reinterpret_cast<const f16x8*>(&Bs[wc + fr][kl]);
        f16x8 b1 = *reinterpret_cast<const f16x8*>(&Bs[wc + 16 + fr][kl]);
        acc[0][0] = __builtin_amdgcn_mfma_f32_16x16x32_f16(a0, b0, acc[0][0], 0, 0, 0);
        acc[0][1] = __builtin_amdgcn_mfma_f32_16x16x32_f16(a0, b1, acc[0][1], 0, 0, 0);
        acc[1][0] = __builtin_amdgcn_mfma_f32_16x16x32_f16(a1, b0, acc[1][0], 0, 0, 0);
        acc[1][1] = __builtin_amdgcn_mfma_f32_16x16x32_f16(a1, b1, acc[1][1], 0, 0, 0);
        __syncthreads();
    }
    for (int fm = 0; fm < 2; ++fm)
        for (int fn = 0; fn < 2; ++fn) {
            int col = n0 + wc + (fn << 4) + fr;
            float bv = bias[col];
            for (int j = 0; j < 4; ++j) {
                int rowg = m0 + wr + (fm << 4) + ((l >> 4) << 2) + j;
                C[(size_t)rowg * NG + col] = (f16)(acc[fm][fn][j] + bv);
            }
        }
}

// --------------------------- persistent GRU recurrence, MFMA, both layers ---------------------------
// 256 WGs x 256 thr (1/CU). Decode: c=blk&7 (cluster -> XCD), l=(blk>>3)&1 (layer),
// gg=blk>>4 (0..15): WG owns 32 outputs. Wave owns 8 outputs = 2 MFMA tiles of 16 rows
// (4 outputs x {r,z,n,pad}). A-frag = recurrent weights, VGPR-resident for the whole
// kernel (zero LDS weight traffic). B-frag = h[batch][k] staged in LDS each step; batch
// cols 0-7 real, 8-15 duplicates (discarded). Gate math fully in-lane (C/D row = out*4+gate).
// Cross-WG h exchange via relaxed agent atomics; ordering from __syncthreads vmcnt drain.
__global__ __launch_bounds__(256) void k_recur3(
        const f16* __restrict__ Wh0p, const f16* __restrict__ Wh1p,
        const f16* __restrict__ Z0, const f16* __restrict__ Z1,
        const float* __restrict__ ghb0, const float* __restrict__ ghb1,
        f16* hb0, f16* hb1, f16* __restrict__ H0out, int* cnt,
        int t00, int n0, int t01, int n1) {
    __shared__ __align__(16) f16 HS[8 * HS_LD];   // staged h: [b][k], stride 536
    __shared__ __align__(16) f16 hx[8][32];       // gathered h_next slice
    const int blk = blockIdx.x;
    const int c = blk & 7;
    const int l = (blk >> 3) & 1;
    const int gg = blk >> 4;                      // 0..15
    const int nsteps = l ? n1 : n0;
    if (nsteps <= 0) return;
    const int t0 = l ? t01 : t00;
    const f16* __restrict__ Wh = l ? Wh1p : Wh0p;
    const f16* __restrict__ Z  = l ? Z1 : Z0;
    const float* __restrict__ ghb = l ? ghb1 : ghb0;
    f16* hbuf = l ? hb1 : hb0;
    int* mycnt = cnt + ((l * 8 + c) << 5);        // 128B apart
    unsigned long long* hb64 = reinterpret_cast<unsigned long long*>(hbuf);

    const int i0 = gg << 5;                       // WG's first output
    const int tid = threadIdx.x;
    const int w = tid >> 6;                       // wave 0..3 -> outputs i0+8w..+8w+7
    const int lane = tid & 63;
    const int colb = lane & 15;                   // C/D col (batch slot; 8-15 dup)
    const int bq = lane & 7;                      // real batch within cluster
    const int j4 = lane >> 4;                     // k-octet for A/B frags; out-group for C/D
    // A-frag row decode: row = ol*4 + gate (gate 3 = zero pad row)
    const int rrow = lane & 15;
    const int ol = rrow >> 2, gate = rrow & 3;

    // ---- preload recurrent weights into VGPRs (per-thread constant all steps) ----
    f16x8 wA[2][16];
    #pragma unroll
    for (int tl = 0; tl < 2; ++tl) {
        const int out = i0 + (w << 3) + (tl << 2) + ol;
        #pragma unroll
        for (int t = 0; t < 16; ++t) {
            f16x8 v{};
            if (gate < 3)
                v = *reinterpret_cast<const f16x8*>(
                        Wh + ((size_t)(gate * H_ + out)) * H_ + (t << 5) + (j4 << 3));
            wA[tl][t] = v;
        }
    }
    // per-lane outputs for gate math (C/D rows j4*4+j)
    const int outA = i0 + (w << 3) + j4;          // tile 0
    const int outB = outA + 4;                    // tile 1
    const float gbA = ghb[outA], gbB = ghb[outB];

    for (int sl = 0; sl < nsteps; ++sl) {
        const int s = t0 + sl;
        const int p = s & 1;
        // ---- Z prefetch (independent of h; hides under spin + stage) ----
        const size_t zrow = ((size_t)sl * 64 + (c << 3) + bq) * NG;
        float zrA = (float)Z[zrow + outA];
        float zzA = (float)Z[zrow + H_ + outA];
        float znA = (float)Z[zrow + 2 * H_ + outA];
        float zrB = (float)Z[zrow + outB];
        float zzB = (float)Z[zrow + H_ + outB];
        float znB = (float)Z[zrow + 2 * H_ + outB];
        // ---- wait for cluster to finish step s-1 ----
        if (tid == 0) {
            const int target = s << 4;            // 16 WGs per cluster-layer
            while (__hip_atomic_load(mycnt, __ATOMIC_RELAXED, __HIP_MEMORY_SCOPE_AGENT) < target) {}
        }
        __syncthreads();
        // ---- stage h[p] (8 batches x 512) into LDS via bypassing atomic loads ----
        {
            const size_t srcb = ((size_t)p * 64 + (c << 3)) * 128;   // ull units
            #pragma unroll
            for (int it = 0; it < 4; ++it) {
                int idx = tid + (it << 8);
                int b = idx >> 7, kq = idx & 127;
                unsigned long long v = __hip_atomic_load(hb64 + srcb + (b << 7) + kq,
                        __ATOMIC_RELAXED, __HIP_MEMORY_SCOPE_AGENT);
                *reinterpret_cast<unsigned long long*>(&HS[b * HS_LD + (kq << 2)]) = v;
            }
        }
        __syncthreads();
        // ---- MFMA: 2 tiles x K=512 (16 k-steps), B-frag shared across tiles ----
        f32x4 a00{}, a01{}, a10{}, a11{};
        #pragma unroll
        for (int t = 0; t < 16; ++t) {
            f16x8 bf = *reinterpret_cast<const f16x8*>(&HS[bq * HS_LD + (t << 5) + (j4 << 3)]);
            if (t & 1) {
                a01 = __builtin_amdgcn_mfma_f32_16x16x32_f16(wA[0][t], bf, a01, 0, 0, 0);
                a11 = __builtin_amdgcn_mfma_f32_16x16x32_f16(wA[1][t], bf, a11, 0, 0, 0);
            } else {
                a00 = __builtin_amdgcn_mfma_f32_16x16x32_f16(wA[0][t], bf, a00, 0, 0, 0);
                a10 = __builtin_amdgcn_mfma_f32_16x16x32_f16(wA[1][t], bf, a10, 0, 0, 0);
            }
        }
        f32x4 dA = a00 + a01;                     // rows: outA {r,z,n,pad}
        f32x4 dB = a10 + a11;                     // rows: outB {r,z,n,pad}
        // ---- gate math, fully in-lane; only cols 0-7 are real ----
        if (colb < 8) {
            float holdA = (float)HS[bq * HS_LD + outA];
            float holdB = (float)HS[bq * HS_LD + outB];
            float rA = sigm(zrA + dA[0]);
            float zA = sigm(zzA + dA[1]);
            float nA = tanhf(znA + rA * (dA[2] + gbA));
            float rB = sigm(zrB + dB[0]);
            float zB = sigm(zzB + dB[1]);
            float nB = tanhf(znB + rB * (dB[2] + gbB));
            hx[bq][(w << 3) + j4]     = (f16)((1.f - zA) * nA + zA * holdA);
            hx[bq][(w << 3) + 4 + j4] = (f16)((1.f - zB) * nB + zB * holdB);
        }
        __syncthreads();
        // ---- gather + publish h_next (bypassing atomic stores) + H0 trajectory ----
        if (tid < 64) {
            int b = tid >> 3, seg = tid & 7;
            uint2 v = *reinterpret_cast<const uint2*>(&hx[b][seg << 2]);
            size_t dst = ((size_t)(p ^ 1) * 64 + (c << 3) + b) * 128 + (i0 >> 2) + seg;
            __hip_atomic_store(hb64 + dst, __builtin_bit_cast(unsigned long long, v),
                               __ATOMIC_RELAXED, __HIP_MEMORY_SCOPE_AGENT);
            if (l == 0)
                *reinterpret_cast<uint2*>(
                    &H0out[((size_t)sl * 64 + (c << 3) + b) * H_ + i0 + (seg << 2)]) = v;
        }
        __syncthreads();   // vmcnt(0) drained before barrier -> stores complete
        if (tid == 0)
            __hip_atomic_fetch_add(mycnt, 1, __ATOMIC_RELAXED, __HIP_MEMORY_SCOPE_AGENT);
    }
}

// ------------------------------- final head -------------------------------
__global__ __launch_bounds__(64) void k_final(const f16* __restrict__ h,
        const float* __restrict__ fcw, const float* __restrict__ fcb,
        float* __restrict__ out) {
    int b = threadIdx.x;
    float acc = fcb[0];
    for (int k = 0; k < H_; ++k) acc += (float)h[(size_t)b * H_ + k] * fcw[k];
    out[b] = sigm(acc);
}

extern "C" void kernel_launch(void* const* d_in, const int* in_sizes, int n_in,
                              void* d_out, int out_size, void* d_ws, size_t ws_size,
                              hipStream_t stream) {
    (void)in_sizes; (void)n_in; (void)out_size; (void)ws_size;
    const int*   tokens = (const int*)d_in[0];
    const float* emb  = (const float*)d_in[1];
    const float* fc_w = (const float*)d_in[2];
    const float* fc_b = (const float*)d_in[3];
    const float* gw0  = (const float*)d_in[4];
    const float* gb0  = (const float*)d_in[5];
    const float* giw0 = (const float*)d_in[6];
    const float* gib0 = (const float*)d_in[7];
    const float* ghw0 = (const float*)d_in[8];
    const float* ghb0 = (const float*)d_in[9];
    const float* gw1  = (const float*)d_in[10];
    const float* gb1  = (const float*)d_in[11];
    const float* giw1 = (const float*)d_in[12];
    const float* gib1 = (const float*)d_in[13];
    const float* ghw1 = (const float*)d_in[14];
    const float* ghb1 = (const float*)d_in[15];

    char* base = (char*)d_ws;
    size_t off = 0;
    auto carve = [&](size_t bytes) {
        char* p = base + off;
        off = (off + bytes + 255) & ~(size_t)255;
        return p;
    };
    f16*   Wx0   = (f16*)carve((size_t)NG * 256 * 2);
    f16*   Wh0   = (f16*)carve((size_t)NG * 512 * 2);
    f16*   Wx1   = (f16*)carve((size_t)NG * 512 * 2);
    f16*   Wh1   = (f16*)carve((size_t)NG * 512 * 2);
    float* bias0 = (float*)carve(NG * 4);
    float* bias1 = (float*)carve(NG * 4);
    f16*   hbuf0 = (f16*)carve((size_t)2 * B_ * H_ * 2);
    f16*   hbuf1 = (f16*)carve((size_t)2 * B_ * H_ * 2);
    int*   cnt   = (int*)carve((size_t)16 * 32 * 4);
    f16*   Xc    = (f16*)carve((size_t)ROWS_CH * 256 * 2);
    f16*   Zc0   = (f16*)carve((size_t)ROWS_CH * NG * 2);
    f16*   H0c   = (f16*)carve((size_t)ROWS_CH * 512 * 2);
    f16*   Zc1   = (f16*)carve((size_t)ROWS_CH * NG * 2);

    hipMemsetAsync(hbuf0, 0, (size_t)2 * B_ * H_ * 2, stream);
    hipMemsetAsync(hbuf1, 0, (size_t)2 * B_ * H_ * 2, stream);
    hipMemsetAsync(cnt, 0, (size_t)16 * 32 * 4, stream);

    k_packW<<<384, 256, 0, stream>>>(gw0, 768, 0,    giw0, Wx0, 256);
    k_packW<<<768, 256, 0, stream>>>(gw0, 768, 256,  ghw0, Wh0, 512);
    k_packW<<<768, 256, 0, stream>>>(gw1, 1024, 0,   giw1, Wx1, 512);
    k_packW<<<768, 256, 0, stream>>>(gw1, 1024, 512, ghw1, Wh1, 512);
    k_packBias<<<6, 256, 0, stream>>>(gb0, gib0, bias0);
    k_packBias<<<6, 256, 0, stream>>>(gb1, gib1, bias1);

    dim3 gemmGrid(NG / 64, ROWS_CH / 64);   // (24, 128)
    for (int ch = 0; ch < NCHUNK; ++ch) {
        int t0 = ch * TCH;
        k_embed<<<ROWS_CH * 64 / 256, 256, 0, stream>>>(tokens, emb, Xc, t0);
        k_gemm<<<gemmGrid, 256, 0, stream>>>(Xc, Wx0, bias0, Zc0, 256);
        // L0 of chunk ch runs concurrently with L1 of chunk ch-1
        k_recur3<<<256, 256, 0, stream>>>(Wh0, Wh1, Zc0, Zc1, ghb0, ghb1,
                                          hbuf0, hbuf1, H0c, cnt,
                                          t0, TCH, t0 - TCH, ch ? TCH : 0);
        k_gemm<<<gemmGrid, 256, 0, stream>>>(H0c, Wx1, bias1, Zc1, 512);
    }
    // drain: last chunk of layer 1
    k_recur3<<<256, 256, 0, stream>>>(Wh0, Wh1, Zc0, Zc1, ghb0, ghb1,
                                      hbuf0, hbuf1, H0c, cnt,
                                      0, 0, (NCHUNK - 1) * TCH, TCH);
    k_final<<<1, 64, 0, stream>>>(hbuf1, fc_w, fc_b, (float*)d_out);
}